// Round 6
// baseline (275.371 us; speedup 1.0000x reference)
//
#include <hip/hip_runtime.h>
#include <hip/hip_bf16.h>

typedef __attribute__((ext_vector_type(4))) float v4f;
typedef __attribute__((ext_vector_type(16))) float v16f;
typedef __attribute__((ext_vector_type(8))) short v8s;
typedef __attribute__((ext_vector_type(4))) unsigned v4u;
typedef __attribute__((ext_vector_type(2))) unsigned v2u;

// full RNE fp32->bf16 (prep kernel only)
__device__ __forceinline__ short f2bf(float f) {
  union { float f; unsigned u; } v; v.f = f;
  unsigned r = v.u + 0x7FFFu + ((v.u >> 16) & 1u);
  return (short)(r >> 16);
}
// packed 2xfp32 -> bf16x2, single v_cvt_pk_bf16_f32
__device__ __forceinline__ unsigned pk2(float a, float b) {
  union { __hip_bfloat162 h; unsigned u; } c;
  c.h = __float22bfloat162_rn(make_float2(a, b));
  return c.u;
}
// bf16x2 dword -> two f32
__device__ __forceinline__ float bflo(unsigned u) {
  union { float f; unsigned u; } v; v.u = u << 16; return v.f;
}
__device__ __forceinline__ float bfhi(unsigned u) {
  union { float f; unsigned u; } v; v.u = u & 0xFFFF0000u; return v.f;
}

// prep: pack W1 [128x256] + W2 [256x256] into 32x32x16 MFMA A-fragment order
// (bf16), and convert x_user/x_movie f32 -> bf16 tables (RNE; identical to the
// old in-register conversion -> same numerics, half the gather bytes).
// 32x32x16 A-operand: lane l of fragment (nt, kt) holds
//   A'[n = nt*32 + (l&31)][k = kt*16 + (l>>5)*8 + j], j = 0..7
__global__ void prep(const float* __restrict__ W1, const float* __restrict__ W2,
                     const float* __restrict__ xu, const float* __restrict__ xm,
                     short* __restrict__ pW1, short* __restrict__ pW2,
                     short* __restrict__ xub, short* __restrict__ xmb,
                     int Nu, int Nm) {
  int tid = blockIdx.x * 256 + threadIdx.x;
  if (tid < 32768) {
    int j = tid & 7, l = (tid >> 3) & 63, frag = tid >> 9;   // frag 0..63
    int nt = frag >> 3, kt = frag & 7;
    int n = nt * 32 + (l & 31);
    int k = kt * 16 + ((l >> 5) * 8) + j;
    pW1[tid] = f2bf(W1[k * 256 + n]);
  } else if (tid < 98304) {
    int t2 = tid - 32768;
    int j = t2 & 7, l = (t2 >> 3) & 63, frag = t2 >> 9;      // frag 0..127
    int nt = frag >> 4, kt = frag & 15;
    int n = nt * 32 + (l & 31);
    int k = kt * 16 + ((l >> 5) * 8) + j;
    pW2[t2] = f2bf(W2[k * 256 + n]);
  } else {
    int c = tid - 98304;
    int tu = Nu * 8;
    int total = tu + Nm * 8;
    if (c < total) {
      const float* s; short* d;
      if (c < tu) { s = xu + (size_t)c * 8; d = xub + (size_t)c * 8; }
      else { int c2 = c - tu; s = xm + (size_t)c2 * 8; d = xmb + (size_t)c2 * 8; }
      v4f a = *(const v4f*)s, b = *(const v4f*)(s + 4);
      v4u o = { pk2(a[0], a[1]), pk2(a[2], a[3]), pk2(b[0], b[1]), pk2(b[2], b[3]) };
      *(v4u*)d = o;
    }
  }
}

#define LDX_S 136   // 128 + 8 pad shorts
#define LDH_S 264   // 256 + 8 pad shorts
#define LDP13 12    // 8 slots + 4 pad floats
#define XBUF (64 * LDX_S)    // 8704 shorts / buffer
#define HBUF (64 * LDH_S)    // 16896 shorts / buffer
#define PBUF13 (64 * LDP13)  // 768 floats / buffer
#define SMEM13 (2*XBUF*2 + 2*HBUF*2 + 2*PBUF13*4)   // 108544 B

// v14 = v13 with the colt loop UNROLLED into 4 independent MFMA chains
// (a[rowt][colt]). v13 diagnosis: latency-bound, not throughput-bound --
// MFMA busy 3380 cyc + VALU 2600 cyc inside a 6860-cyc phase with all
// throughput meters (MFMA instr, conflicts, VALU) improving while time rose.
// With 2 chains, dependent 32x32x16 issues are ~65 SIMD-cyc apart (marginal
// vs its 8-pass latency) and 2 waves/SIMD can't fill the stalls. 4 chains ->
// ~130 cyc between dependent issues (fully pipelined) and each ds_read feeds
// 2 MFMAs. Regs: B ~225, A ~180 (<256 @ 2 waves/SIMD); reads stay JIT (2 live
// v8s), no hoisted bursts (v10 lesson).
__global__ __launch_bounds__(512, 2) void mlp_v14(
    const short* __restrict__ xub, const short* __restrict__ xmb,
    const void* __restrict__ eidx,
    const short* __restrict__ pW1, const short* __restrict__ pW2,
    const float* __restrict__ b1, const float* __restrict__ b2,
    const float* __restrict__ W3, const float* __restrict__ b3,
    float* __restrict__ out, int E)
{
  extern __shared__ __align__(16) char smem[];
  short* ldsX = (short*)smem;                       // [2][XBUF]
  short* ldsH = (short*)(smem + 2 * XBUF * 2);      // [2][HBUF]
  float* ldsP = (float*)(smem + 2 * XBUF * 2 + 2 * HBUF * 2); // [2][PBUF13]

  const int t    = threadIdx.x;
  const int w    = t >> 6;
  const int lane = t & 63;
  const int lp5  = lane & 31;
  const int hi   = lane >> 5;
  const int wg   = w >> 1;
  const bool isA = (((w & 1) ^ ((w >> 2) & 1)) == 0);

  const unsigned* ew = (const unsigned*)eidx;
  unsigned oddw = (lane < 32) ? ew[2 * lane + 1] : 0u;
  const bool i64 = (__ballot(oddw != 0u) == 0ull);

  const int ntiles = (E + 63) >> 6;
  const int S   = (int)gridDim.x;
  const int bid = (int)blockIdx.x;
  const int Tb  = (ntiles - bid + S - 1) / S;
  const float bias3 = b3[0];

  if (isA) {
    // ===== producer: gather (bf16) + layer 1 (+ store on wg==0) =====
    const v8s* w1v = (const v8s*)pW1;
    v8s rW1[2][8];                      // 64 VGPR: out rows wg*64 + rowt*32 + (l&31)
#pragma unroll
    for (int rowt = 0; rowt < 2; ++rowt)
#pragma unroll
      for (int kt = 0; kt < 8; ++kt)
        rW1[rowt][kt] = w1v[(((wg * 2 + rowt) * 8) + kt) * 64 + lane];
    v4f rb1[2][4];                      // bias rows wg*64 + rowt*32 + g*8 + hi*4 ..+3
#pragma unroll
    for (int rowt = 0; rowt < 2; ++rowt)
#pragma unroll
      for (int g = 0; g < 4; ++g)
        rb1[rowt][g] = *(const v4f*)(b1 + wg * 64 + rowt * 32 + g * 8 + hi * 4);

    const int ra = wg * 64 + lane;      // 4 threads/edge
    const int gi = ra >> 2, gq = ra & 3;

    auto loadIdx = [&](int tl, int& row, int& col) {
      int gE = tl * 64 + gi;
      if (gE >= E || gE < 0) gE = 0;
      if (i64) {
        const long long* p = (const long long*)eidx;
        row = (int)p[gE]; col = (int)p[(long long)E + gE];
      } else {
        const int* p = (const int*)eidx;
        row = p[gE]; col = p[E + gE];
      }
    };

    v4u u0, u1, m0, m1;
    auto issueUM = [&](int row, int col) {
      const v4u* pu = (const v4u*)(xub + (size_t)row * 64 + gq * 16);
      const v4u* pm = (const v4u*)(xmb + (size_t)col * 64 + gq * 16);
      u0 = pu[0]; u1 = pu[1]; m0 = pm[0]; m1 = pm[1];
    };

    int rowN, colN;
    loadIdx(bid, rowN, colN);
    issueUM(rowN, colN);
    loadIdx(bid + S, rowN, colN);

    for (int k = 0; k <= Tb + 2; ++k) {
      __syncthreads();
      const int pb = k & 1;
      const int tg = bid + k * S;

      // ---- commit prefetched bf16 features -> ldsX[pb]
      if (k < Tb) {
        short* px = &ldsX[pb * XBUF + gi * LDX_S + gq * 16];
        *(v4u*)(px)      = u0;  *(v4u*)(px + 8)  = u1;   // user  -> k 0..63
        *(v4u*)(px + 64) = m0;  *(v4u*)(px + 72) = m1;   // movie -> k 64..127
      }
      // ---- prefetch features(t_{k+1}), indices(t_{k+2})
      if (k + 1 < Tb) {
        issueUM(rowN, colN);
        loadIdx(tg + 2 * S, rowN, colN);
      }

      // ---- reduce + store tile t3 from ldsP[pb^1] (wave wg==0, lane = edge)
      const int t3 = tg - 3 * S;
      if (t3 >= 0 && wg == 0) {
        const v4f* pp = (const v4f*)&ldsP[(pb ^ 1) * PBUF13 + lane * LDP13];
        v4f p0 = pp[0], p1 = pp[1];
        float r = bias3 + (p0[0] + p0[1]) + (p0[2] + p0[3])
                        + (p1[0] + p1[1]) + (p1[2] + p1[3]);
        int o = t3 * 64 + lane;
        if (o < E) out[o] = r;
      }

      // ---- layer 1 of t1 : ldsX[pb^1] -> ldsH[pb^1], 4 chains
      const int t1 = tg - S;
      if (t1 >= 0 && t1 < ntiles) {
        const short* xb = &ldsX[(pb ^ 1) * XBUF];
        short* hb = &ldsH[(pb ^ 1) * HBUF];
        v16f a00, a01, a10, a11;        // [rowt][colt], 64 VGPR
#pragma unroll
        for (int g = 0; g < 4; ++g)
#pragma unroll
          for (int rr = 0; rr < 4; ++rr) {
            a00[4 * g + rr] = rb1[0][g][rr];  a01[4 * g + rr] = rb1[0][g][rr];
            a10[4 * g + rr] = rb1[1][g][rr];  a11[4 * g + rr] = rb1[1][g][rr];
          }
        __builtin_amdgcn_s_setprio(1);
#pragma unroll
        for (int kt = 0; kt < 8; ++kt) {
          v8s b0 = *(const v8s*)&xb[(lp5) * LDX_S + kt * 16 + hi * 8];
          v8s b1 = *(const v8s*)&xb[(32 + lp5) * LDX_S + kt * 16 + hi * 8];
          a00 = __builtin_amdgcn_mfma_f32_32x32x16_bf16(rW1[0][kt], b0, a00, 0, 0, 0);
          a10 = __builtin_amdgcn_mfma_f32_32x32x16_bf16(rW1[1][kt], b0, a10, 0, 0, 0);
          a01 = __builtin_amdgcn_mfma_f32_32x32x16_bf16(rW1[0][kt], b1, a01, 0, 0, 0);
          a11 = __builtin_amdgcn_mfma_f32_32x32x16_bf16(rW1[1][kt], b1, a11, 0, 0, 0);
        }
        __builtin_amdgcn_s_setprio(0);
        // relu + pack + H write: rows wg*64 + rowt*32 + g*8 + hi*4 ..+3
#pragma unroll
        for (int g = 0; g < 4; ++g) {
          v2u pw;
          pw.x = pk2(fmaxf(a00[4 * g + 0], 0.f), fmaxf(a00[4 * g + 1], 0.f));
          pw.y = pk2(fmaxf(a00[4 * g + 2], 0.f), fmaxf(a00[4 * g + 3], 0.f));
          *(v2u*)&hb[(lp5) * LDH_S + wg * 64 + g * 8 + hi * 4] = pw;
          pw.x = pk2(fmaxf(a10[4 * g + 0], 0.f), fmaxf(a10[4 * g + 1], 0.f));
          pw.y = pk2(fmaxf(a10[4 * g + 2], 0.f), fmaxf(a10[4 * g + 3], 0.f));
          *(v2u*)&hb[(lp5) * LDH_S + wg * 64 + 32 + g * 8 + hi * 4] = pw;
          pw.x = pk2(fmaxf(a01[4 * g + 0], 0.f), fmaxf(a01[4 * g + 1], 0.f));
          pw.y = pk2(fmaxf(a01[4 * g + 2], 0.f), fmaxf(a01[4 * g + 3], 0.f));
          *(v2u*)&hb[(32 + lp5) * LDH_S + wg * 64 + g * 8 + hi * 4] = pw;
          pw.x = pk2(fmaxf(a11[4 * g + 0], 0.f), fmaxf(a11[4 * g + 1], 0.f));
          pw.y = pk2(fmaxf(a11[4 * g + 2], 0.f), fmaxf(a11[4 * g + 3], 0.f));
          *(v2u*)&hb[(32 + lp5) * LDH_S + wg * 64 + 32 + g * 8 + hi * 4] = pw;
        }
      }
    }
  } else {
    // ===== consumer: layer 2 + bias/ReLU + W3 fold, 4 chains =====
    const v8s* w2v = (const v8s*)pW2;
    v8s rW2[2][16];                     // 128 VGPR: out rows wg*64 + rowt*32 + (l&31)
#pragma unroll
    for (int rowt = 0; rowt < 2; ++rowt)
#pragma unroll
      for (int kt = 0; kt < 16; ++kt)
        rW2[rowt][kt] = w2v[(((wg * 2 + rowt) * 16) + kt) * 64 + lane];
    // b2 packed bf16 (8 regs; exact for b2==0), W3 f32 (16 regs, precision)
    v2u rb2p[2][4]; v4f rw3[2][4];
#pragma unroll
    for (int rowt = 0; rowt < 2; ++rowt)
#pragma unroll
      for (int g = 0; g < 4; ++g) {
        int o = wg * 64 + rowt * 32 + g * 8 + hi * 4;
        v4f bb = *(const v4f*)(b2 + o);
        rb2p[rowt][g].x = pk2(bb[0], bb[1]);
        rb2p[rowt][g].y = pk2(bb[2], bb[3]);
        rw3[rowt][g] = *(const v4f*)(W3 + o);
      }

    for (int k = 0; k <= Tb + 2; ++k) {
      __syncthreads();
      const int pb = k & 1;
      const int tg = bid + k * S;
      const int t2 = tg - 2 * S;
      if (t2 >= 0 && t2 < ntiles) {
        const short* hbr = &ldsH[pb * HBUF];
        float* pPw = &ldsP[pb * PBUF13];
        v16f a00, a01, a10, a11;        // [rowt][colt], 64 VGPR
#pragma unroll
        for (int g = 0; g < 4; ++g) {
          float l0 = bflo(rb2p[0][g].x), h0 = bfhi(rb2p[0][g].x);
          float l1 = bflo(rb2p[0][g].y), h1 = bfhi(rb2p[0][g].y);
          a00[4 * g + 0] = l0; a00[4 * g + 1] = h0; a00[4 * g + 2] = l1; a00[4 * g + 3] = h1;
          a01[4 * g + 0] = l0; a01[4 * g + 1] = h0; a01[4 * g + 2] = l1; a01[4 * g + 3] = h1;
          float l2 = bflo(rb2p[1][g].x), h2 = bfhi(rb2p[1][g].x);
          float l3 = bflo(rb2p[1][g].y), h3 = bfhi(rb2p[1][g].y);
          a10[4 * g + 0] = l2; a10[4 * g + 1] = h2; a10[4 * g + 2] = l3; a10[4 * g + 3] = h3;
          a11[4 * g + 0] = l2; a11[4 * g + 1] = h2; a11[4 * g + 2] = l3; a11[4 * g + 3] = h3;
        }
        __builtin_amdgcn_s_setprio(1);
#pragma unroll
        for (int kt = 0; kt < 16; ++kt) {
          v8s b0 = *(const v8s*)&hbr[(lp5) * LDH_S + kt * 16 + hi * 8];
          v8s b1 = *(const v8s*)&hbr[(32 + lp5) * LDH_S + kt * 16 + hi * 8];
          a00 = __builtin_amdgcn_mfma_f32_32x32x16_bf16(rW2[0][kt], b0, a00, 0, 0, 0);
          a10 = __builtin_amdgcn_mfma_f32_32x32x16_bf16(rW2[1][kt], b0, a10, 0, 0, 0);
          a01 = __builtin_amdgcn_mfma_f32_32x32x16_bf16(rW2[0][kt], b1, a01, 0, 0, 0);
          a11 = __builtin_amdgcn_mfma_f32_32x32x16_bf16(rW2[1][kt], b1, a11, 0, 0, 0);
        }
        __builtin_amdgcn_s_setprio(0);
        float s0 = 0.f, s1 = 0.f;
#pragma unroll
        for (int g = 0; g < 4; ++g)
#pragma unroll
          for (int rr = 0; rr < 4; ++rr) {
            s0 += fmaxf(a00[4 * g + rr], 0.f) * rw3[0][g][rr];
            s0 += fmaxf(a10[4 * g + rr], 0.f) * rw3[1][g][rr];
            s1 += fmaxf(a01[4 * g + rr], 0.f) * rw3[0][g][rr];
            s1 += fmaxf(a11[4 * g + rr], 0.f) * rw3[1][g][rr];
          }
        pPw[(lp5) * LDP13 + wg * 2 + hi] = s0;
        pPw[(32 + lp5) * LDP13 + wg * 2 + hi] = s1;
      }
    }
  }
}

extern "C" void kernel_launch(void* const* d_in, const int* in_sizes, int n_in,
                              void* d_out, int out_size, void* d_ws, size_t ws_size,
                              hipStream_t stream) {
  const float* xu  = (const float*)d_in[0];
  const float* xm  = (const float*)d_in[1];
  const void*  ei  = d_in[2];
  const float* W1  = (const float*)d_in[3];
  const float* b1  = (const float*)d_in[4];
  const float* W2  = (const float*)d_in[5];
  const float* b2  = (const float*)d_in[6];
  const float* W3  = (const float*)d_in[7];
  const float* b3  = (const float*)d_in[8];
  float* out = (float*)d_out;

  const int E  = in_sizes[2] / 2;
  const int Nu = in_sizes[0] / 64;
  const int Nm = in_sizes[1] / 64;

  short* pW1 = (short*)d_ws;          // 64 KB
  short* pW2 = pW1 + 32768;           // 128 KB
  short* xub = (short*)((char*)d_ws + 196608);
  short* xmb = xub + (size_t)Nu * 64;

  const int cvt_blocks = ((Nu + Nm) * 8 + 255) / 256;
  hipLaunchKernelGGL(prep, dim3(384 + cvt_blocks), dim3(256), 0, stream,
                     W1, W2, xu, xm, pW1, pW2, xub, xmb, Nu, Nm);

  hipFuncSetAttribute((const void*)mlp_v14,
                      hipFuncAttributeMaxDynamicSharedMemorySize, SMEM13);

  const int ntiles = (E + 63) / 64;
  const int nblk = ntiles < 256 ? ntiles : 256;
  hipLaunchKernelGGL(mlp_v14, dim3(nblk), dim3(512), SMEM13, stream,
                     xub, xmb, ei, pW1, pW2, b1, b2, W3, b3, out, E);
}

// Round 7
// 271.387 us; speedup vs baseline: 1.0147x; 1.0147x over previous
//
#include <hip/hip_runtime.h>
#include <hip/hip_bf16.h>

typedef __attribute__((ext_vector_type(4))) float v4f;
typedef __attribute__((ext_vector_type(8))) short v8s;
typedef __attribute__((ext_vector_type(4))) unsigned v4u;
typedef __attribute__((ext_vector_type(2))) unsigned v2u;

// full RNE fp32->bf16 (prep kernel only)
__device__ __forceinline__ short f2bf(float f) {
  union { float f; unsigned u; } v; v.f = f;
  unsigned r = v.u + 0x7FFFu + ((v.u >> 16) & 1u);
  return (short)(r >> 16);
}
// packed 2xfp32 -> bf16x2, single v_cvt_pk_bf16_f32
__device__ __forceinline__ unsigned pk2(float a, float b) {
  union { __hip_bfloat162 h; unsigned u; } c;
  c.h = __float22bfloat162_rn(make_float2(a, b));
  return c.u;
}

// prep: pack W1 [128x256] + W2 [256x256] into bf16 MFMA A-fragment order
// (16x16x32: lane l of frag (mt,kt) holds A'[n=mt*16+(l&15)][k=kt*32+(l>>4)*8+j])
// and convert x_user/x_movie f32 -> bf16 tables (RNE; identical numerics to
// in-register conversion, half the gather bytes, cache-resident working set).
__global__ void prep(const float* __restrict__ W1, const float* __restrict__ W2,
                     const float* __restrict__ xu, const float* __restrict__ xm,
                     short* __restrict__ pW1, short* __restrict__ pW2,
                     short* __restrict__ xub, short* __restrict__ xmb,
                     int Nu, int Nm) {
  int tid = blockIdx.x * 256 + threadIdx.x;
  if (tid < 32768) {
    int j = tid & 7, l = (tid >> 3) & 63, frag = tid >> 9;
    int mt = frag >> 2, kt = frag & 3;
    int n = mt * 16 + (l & 15);
    int k = kt * 32 + ((l >> 4) * 8) + j;
    pW1[tid] = f2bf(W1[k * 256 + n]);
  } else if (tid < 98304) {
    int t2 = tid - 32768;
    int j = t2 & 7, l = (t2 >> 3) & 63, frag = t2 >> 9;
    int mt = frag >> 3, kt = frag & 7;
    int n = mt * 16 + (l & 15);
    int k = kt * 32 + ((l >> 4) * 8) + j;
    pW2[t2] = f2bf(W2[k * 256 + n]);
  } else {
    int c = tid - 98304;
    int tu = Nu * 8;
    int total = tu + Nm * 8;
    if (c < total) {
      const float* s; short* d;
      if (c < tu) { s = xu + (size_t)c * 8; d = xub + (size_t)c * 8; }
      else { int c2 = c - tu; s = xm + (size_t)c2 * 8; d = xmb + (size_t)c2 * 8; }
      v4f a = *(const v4f*)s, b = *(const v4f*)(s + 4);
      v4u o = { pk2(a[0], a[1]), pk2(a[2], a[3]), pk2(b[0], b[1]), pk2(b[2], b[3]) };
      *(v4u*)d = o;
    }
  }
}

#define LDX_S 136   // 128 + 8 pad shorts
#define LDH_S 264   // 256 + 8 pad shorts
#define LDP_S 40    // 32 slots + 8 pad floats
#define XBUF (64 * LDX_S)   // 8704 shorts / buffer
#define HBUF (64 * LDH_S)   // 16896 shorts / buffer
#define PBUF (64 * LDP_S)   // 2560 floats / buffer
#define SMEM_BYTES (2*XBUF*2 + 2*HBUF*2 + 2*PBUF*4)   // 122880

// v15 = v12 (proven 172 us) with MFMA REBALANCED 96/96 across roles.
// v12 diagnosis: B-wave path (~3100 cyc: 128 MFMA + 32 ds_read + fold) is
// ~1100 cyc longer than A's (~2000); the phase barrier locks both to the max,
// so A idles every phase while LDS (43%) and MFMA (58%) pipes both have slack.
// v15: each A-wave takes the mi=0 slice (16 output rows) of its wg's layer-2:
//   A: commit X + gather + P-store(wg0) + L1 (64 MFMA) + L2-mi0 (32 MFMA)
//   B: L2 mi=1..3 (96 MFMA) + fold
// Cost: A adds 32 ds_read_b128/phase (duplicated H B-frags) -> LDS ~55%.
// Regs: A ~200, B ~165 (both < spill cliff ~280 demand seen in v10/v14).
// P now has 32 partial slots (16 B + 16 A).
__global__ __launch_bounds__(512, 2) void mlp_v15(
    const short* __restrict__ xub, const short* __restrict__ xmb,
    const void* __restrict__ eidx,
    const short* __restrict__ pW1, const short* __restrict__ pW2,
    const float* __restrict__ b1, const float* __restrict__ b2,
    const float* __restrict__ W3, const float* __restrict__ b3,
    float* __restrict__ out, int E)
{
  extern __shared__ __align__(16) char smem[];
  short* ldsX = (short*)smem;                       // [2][XBUF]
  short* ldsH = (short*)(smem + 2 * XBUF * 2);      // [2][HBUF]
  float* ldsP = (float*)(smem + 2 * XBUF * 2 + 2 * HBUF * 2); // [2][PBUF]

  const int t    = threadIdx.x;
  const int w    = t >> 6;
  const int lane = t & 63;
  const int quad = lane >> 4;
  const int lp   = lane & 15;
  const int wg   = w >> 1;
  const bool isA = (((w & 1) ^ ((w >> 2) & 1)) == 0);

  const unsigned* ew = (const unsigned*)eidx;
  unsigned oddw = (lane < 32) ? ew[2 * lane + 1] : 0u;
  const bool i64 = (__ballot(oddw != 0u) == 0ull);

  const int ntiles = (E + 63) >> 6;
  const int S   = (int)gridDim.x;
  const int bid = (int)blockIdx.x;
  const int Tb  = (ntiles - bid + S - 1) / S;
  const float bias3 = b3[0];

  if (isA) {
    // ===== producer: gather + L1 + L2-mi0 slice (+ P-store on wg==0) =====
    const v8s* w1v = (const v8s*)pW1;
    v8s rW1[4][4];                      // 64 VGPR
#pragma unroll
    for (int mi = 0; mi < 4; ++mi)
#pragma unroll
      for (int kt = 0; kt < 4; ++kt)
        rW1[mi][kt] = w1v[(((wg * 4 + mi) * 4) + kt) * 64 + lane];
    v4f rb1[4];
#pragma unroll
    for (int mi = 0; mi < 4; ++mi)
      rb1[mi] = *(const v4f*)(b1 + wg * 64 + mi * 16 + quad * 4);

    // L2 slice mi=0 of this wg: rows wg*64 .. wg*64+15
    const v8s* w2v = (const v8s*)pW2;
    v8s rW2a[8];                        // 32 VGPR
#pragma unroll
    for (int kt = 0; kt < 8; ++kt)
      rW2a[kt] = w2v[(((wg * 4 + 0) * 8) + kt) * 64 + lane];
    const int nh0a = wg * 64 + quad * 4;
    const v4f rb2a = *(const v4f*)(b2 + nh0a);
    const v4f rw3a = *(const v4f*)(W3 + nh0a);

    const int ra = wg * 64 + lane;      // 4 threads/edge
    const int gi = ra >> 2, gq = ra & 3;

    auto loadIdx = [&](int tl, int& row, int& col) {
      int gE = tl * 64 + gi;
      if (gE >= E || gE < 0) gE = 0;
      if (i64) {
        const long long* p = (const long long*)eidx;
        row = (int)p[gE]; col = (int)p[(long long)E + gE];
      } else {
        const int* p = (const int*)eidx;
        row = p[gE]; col = p[E + gE];
      }
    };

    v4u u0, u1, m0, m1;
    auto issueUM = [&](int row, int col) {
      const v4u* pu = (const v4u*)(xub + (size_t)row * 64 + gq * 16);
      const v4u* pm = (const v4u*)(xmb + (size_t)col * 64 + gq * 16);
      u0 = pu[0]; u1 = pu[1]; m0 = pm[0]; m1 = pm[1];
    };

    int rowN, colN;
    loadIdx(bid, rowN, colN);
    issueUM(rowN, colN);
    loadIdx(bid + S, rowN, colN);

    for (int k = 0; k <= Tb + 2; ++k) {
      __syncthreads();
      const int pb = k & 1;
      const int tg = bid + k * S;

      // ---- commit prefetched bf16 features -> ldsX[pb]
      if (k < Tb) {
        short* px = &ldsX[pb * XBUF + gi * LDX_S + gq * 16];
        *(v4u*)(px)      = u0;  *(v4u*)(px + 8)  = u1;   // user  -> k 0..63
        *(v4u*)(px + 64) = m0;  *(v4u*)(px + 72) = m1;   // movie -> k 64..127
      }
      // ---- prefetch features(t_{k+1}), indices(t_{k+2})
      if (k + 1 < Tb) {
        issueUM(rowN, colN);
        loadIdx(tg + 2 * S, rowN, colN);
      }

      // ---- reduce + store tile t3 from ldsP[pb^1] (wave wg==0, lane = edge)
      const int t3 = tg - 3 * S;
      if (t3 >= 0 && wg == 0) {
        const v4f* pp = (const v4f*)&ldsP[(pb ^ 1) * PBUF + lane * LDP_S];
        float r = bias3;
#pragma unroll
        for (int c = 0; c < 8; ++c) {
          v4f p = pp[c];
          r += (p[0] + p[1]) + (p[2] + p[3]);
        }
        int o = t3 * 64 + lane;
        if (o < E) out[o] = r;
      }

      // ---- layer 1 of t1 : ldsX[pb^1] -> ldsH[pb^1]
      const int t1 = tg - S;
      if (t1 >= 0 && t1 < ntiles) {
        const short* xb = &ldsX[(pb ^ 1) * XBUF];
#pragma unroll 1
        for (int nh = 0; nh < 2; ++nh) {       // ni halves: acc live = 32 VGPR
          v4f acc[4][2];
#pragma unroll
          for (int mi = 0; mi < 4; ++mi) { acc[mi][0] = rb1[mi]; acc[mi][1] = rb1[mi]; }
          __builtin_amdgcn_s_setprio(1);
#pragma unroll
          for (int kt = 0; kt < 4; ++kt) {
            v8s bf0 = *(const v8s*)&xb[((nh * 2 + 0) * 16 + lp) * LDX_S + kt * 32 + quad * 8];
            v8s bf1 = *(const v8s*)&xb[((nh * 2 + 1) * 16 + lp) * LDX_S + kt * 32 + quad * 8];
#pragma unroll
            for (int mi = 0; mi < 4; ++mi) {
              acc[mi][0] = __builtin_amdgcn_mfma_f32_16x16x32_bf16(rW1[mi][kt], bf0, acc[mi][0], 0, 0, 0);
              acc[mi][1] = __builtin_amdgcn_mfma_f32_16x16x32_bf16(rW1[mi][kt], bf1, acc[mi][1], 0, 0, 0);
            }
          }
          __builtin_amdgcn_s_setprio(0);
#pragma unroll
          for (int mi = 0; mi < 4; ++mi) {
            int nh0 = wg * 64 + mi * 16 + quad * 4;
#pragma unroll
            for (int nj = 0; nj < 2; ++nj) {
              int e = (nh * 2 + nj) * 16 + lp;
              v4f v = acc[mi][nj];
              v2u pw; pw.x = pk2(fmaxf(v[0], 0.f), fmaxf(v[1], 0.f));
              pw.y = pk2(fmaxf(v[2], 0.f), fmaxf(v[3], 0.f));
              *(v2u*)&ldsH[(pb ^ 1) * HBUF + e * LDH_S + nh0] = pw;
            }
          }
        }
      }

      // ---- layer 2 slice (mi=0) of t2 : ldsH[pb] -> ldsP[pb] slots 16..31
      const int t2 = tg - 2 * S;
      if (t2 >= 0 && t2 < ntiles) {
        const short* hbr = &ldsH[pb * HBUF];
        float* pPw = &ldsP[pb * PBUF];
#pragma unroll 1
        for (int nh = 0; nh < 2; ++nh) {
          v4f a0 = rb2a, a1 = rb2a;
          __builtin_amdgcn_s_setprio(1);
#pragma unroll
          for (int kt = 0; kt < 8; ++kt) {
            v8s bf0 = *(const v8s*)&hbr[((nh * 2 + 0) * 16 + lp) * LDH_S + kt * 32 + quad * 8];
            v8s bf1 = *(const v8s*)&hbr[((nh * 2 + 1) * 16 + lp) * LDH_S + kt * 32 + quad * 8];
            a0 = __builtin_amdgcn_mfma_f32_16x16x32_bf16(rW2a[kt], bf0, a0, 0, 0, 0);
            a1 = __builtin_amdgcn_mfma_f32_16x16x32_bf16(rW2a[kt], bf1, a1, 0, 0, 0);
          }
          __builtin_amdgcn_s_setprio(0);
          float s0 = 0.f, s1 = 0.f;
#pragma unroll
          for (int r = 0; r < 4; ++r) {
            s0 += fmaxf(a0[r], 0.f) * rw3a[r];
            s1 += fmaxf(a1[r], 0.f) * rw3a[r];
          }
          int e0 = (nh * 2 + 0) * 16 + lp, e1 = (nh * 2 + 1) * 16 + lp;
          pPw[e0 * LDP_S + 16 + wg * 4 + quad] = s0;
          pPw[e1 * LDP_S + 16 + wg * 4 + quad] = s1;
        }
      }
    }
  } else {
    // ===== consumer: layer 2 mi=1..3 + bias/ReLU + W3 fold =====
    const v8s* w2v = (const v8s*)pW2;
    v8s rW2[3][8];                      // 96 VGPR: rows wg*64+16 .. wg*64+63
#pragma unroll
    for (int m = 0; m < 3; ++m)
#pragma unroll
      for (int kt = 0; kt < 8; ++kt)
        rW2[m][kt] = w2v[(((wg * 4 + (m + 1)) * 8) + kt) * 64 + lane];
    v4f rb2[3], rw3[3];
#pragma unroll
    for (int m = 0; m < 3; ++m) {
      int nh0 = wg * 64 + (m + 1) * 16 + quad * 4;
      rb2[m] = *(const v4f*)(b2 + nh0);
      rw3[m] = *(const v4f*)(W3 + nh0);
    }

    for (int k = 0; k <= Tb + 2; ++k) {
      __syncthreads();
      const int pb = k & 1;
      const int tg = bid + k * S;
      const int t2 = tg - 2 * S;
      if (t2 >= 0 && t2 < ntiles) {
        const short* hbr = &ldsH[pb * HBUF];
        float* pPw = &ldsP[pb * PBUF];
#pragma unroll 1
        for (int nh = 0; nh < 2; ++nh) {       // ni halves: acc live = 24 VGPR
          v4f acc2[3][2];
#pragma unroll
          for (int m = 0; m < 3; ++m) { acc2[m][0] = rb2[m]; acc2[m][1] = rb2[m]; }
          __builtin_amdgcn_s_setprio(1);
#pragma unroll
          for (int kt = 0; kt < 8; ++kt) {
            v8s bf0 = *(const v8s*)&hbr[((nh * 2 + 0) * 16 + lp) * LDH_S + kt * 32 + quad * 8];
            v8s bf1 = *(const v8s*)&hbr[((nh * 2 + 1) * 16 + lp) * LDH_S + kt * 32 + quad * 8];
#pragma unroll
            for (int m = 0; m < 3; ++m) {
              acc2[m][0] = __builtin_amdgcn_mfma_f32_16x16x32_bf16(rW2[m][kt], bf0, acc2[m][0], 0, 0, 0);
              acc2[m][1] = __builtin_amdgcn_mfma_f32_16x16x32_bf16(rW2[m][kt], bf1, acc2[m][1], 0, 0, 0);
            }
          }
          __builtin_amdgcn_s_setprio(0);
          float s0 = 0.f, s1 = 0.f;
#pragma unroll
          for (int m = 0; m < 3; ++m) {
#pragma unroll
            for (int r = 0; r < 4; ++r) {
              s0 += fmaxf(acc2[m][0][r], 0.f) * rw3[m][r];
              s1 += fmaxf(acc2[m][1][r], 0.f) * rw3[m][r];
            }
          }
          int e0 = (nh * 2 + 0) * 16 + lp, e1 = (nh * 2 + 1) * 16 + lp;
          pPw[e0 * LDP_S + wg * 4 + quad] = s0;
          pPw[e1 * LDP_S + wg * 4 + quad] = s1;
        }
      }
    }
  }
}

extern "C" void kernel_launch(void* const* d_in, const int* in_sizes, int n_in,
                              void* d_out, int out_size, void* d_ws, size_t ws_size,
                              hipStream_t stream) {
  const float* xu  = (const float*)d_in[0];
  const float* xm  = (const float*)d_in[1];
  const void*  ei  = d_in[2];
  const float* W1  = (const float*)d_in[3];
  const float* b1  = (const float*)d_in[4];
  const float* W2  = (const float*)d_in[5];
  const float* b2  = (const float*)d_in[6];
  const float* W3  = (const float*)d_in[7];
  const float* b3  = (const float*)d_in[8];
  float* out = (float*)d_out;

  const int E  = in_sizes[2] / 2;
  const int Nu = in_sizes[0] / 64;
  const int Nm = in_sizes[1] / 64;

  short* pW1 = (short*)d_ws;          // 64 KB
  short* pW2 = pW1 + 32768;           // 128 KB
  short* xub = (short*)((char*)d_ws + 196608);
  short* xmb = xub + (size_t)Nu * 64;

  const int cvt_blocks = ((Nu + Nm) * 8 + 255) / 256;
  hipLaunchKernelGGL(prep, dim3(384 + cvt_blocks), dim3(256), 0, stream,
                     W1, W2, xu, xm, pW1, pW2, xub, xmb, Nu, Nm);

  hipFuncSetAttribute((const void*)mlp_v15,
                      hipFuncAttributeMaxDynamicSharedMemorySize, SMEM_BYTES);

  const int ntiles = (E + 63) / 64;
  const int nblk = ntiles < 256 ? ntiles : 256;
  hipLaunchKernelGGL(mlp_v15, dim3(nblk), dim3(512), SMEM_BYTES, stream,
                     xub, xmb, ei, pW1, pW2, b1, b2, W3, b3, out, E);
}

// Round 8
// 248.285 us; speedup vs baseline: 1.1091x; 1.0930x over previous
//
#include <hip/hip_runtime.h>
#include <hip/hip_bf16.h>

typedef __attribute__((ext_vector_type(4))) float v4f;
typedef __attribute__((ext_vector_type(8))) short v8s;
typedef __attribute__((ext_vector_type(4))) unsigned v4u;
typedef __attribute__((ext_vector_type(2))) unsigned v2u;

// full RNE fp32->bf16 (prep kernel only)
__device__ __forceinline__ short f2bf(float f) {
  union { float f; unsigned u; } v; v.f = f;
  unsigned r = v.u + 0x7FFFu + ((v.u >> 16) & 1u);
  return (short)(r >> 16);
}
// packed 2xfp32 -> bf16x2, single v_cvt_pk_bf16_f32
__device__ __forceinline__ unsigned pk2(float a, float b) {
  union { __hip_bfloat162 h; unsigned u; } c;
  c.h = __float22bfloat162_rn(make_float2(a, b));
  return c.u;
}

// prep: pack W1 [128x256] + W2 [256x256] into bf16 MFMA A-fragment order
// (16x16x32: lane l of frag (mt,kt) holds A'[n=mt*16+(l&15)][k=kt*32+(l>>4)*8+j])
// and convert x_user/x_movie f32 -> bf16 tables (RNE; identical numerics to
// in-register conversion, half the gather bytes, cache-resident working set).
__global__ void prep(const float* __restrict__ W1, const float* __restrict__ W2,
                     const float* __restrict__ xu, const float* __restrict__ xm,
                     short* __restrict__ pW1, short* __restrict__ pW2,
                     short* __restrict__ xub, short* __restrict__ xmb,
                     int Nu, int Nm) {
  int tid = blockIdx.x * 256 + threadIdx.x;
  if (tid < 32768) {
    int j = tid & 7, l = (tid >> 3) & 63, frag = tid >> 9;
    int mt = frag >> 2, kt = frag & 3;
    int n = mt * 16 + (l & 15);
    int k = kt * 32 + ((l >> 4) * 8) + j;
    pW1[tid] = f2bf(W1[k * 256 + n]);
  } else if (tid < 98304) {
    int t2 = tid - 32768;
    int j = t2 & 7, l = (t2 >> 3) & 63, frag = t2 >> 9;
    int mt = frag >> 3, kt = frag & 7;
    int n = mt * 16 + (l & 15);
    int k = kt * 32 + ((l >> 4) * 8) + j;
    pW2[t2] = f2bf(W2[k * 256 + n]);
  } else {
    int c = tid - 98304;
    int tu = Nu * 8;
    int total = tu + Nm * 8;
    if (c < total) {
      const float* s; short* d;
      if (c < tu) { s = xu + (size_t)c * 8; d = xub + (size_t)c * 8; }
      else { int c2 = c - tu; s = xm + (size_t)c2 * 8; d = xmb + (size_t)c2 * 8; }
      v4f a = *(const v4f*)s, b = *(const v4f*)(s + 4);
      v4u o = { pk2(a[0], a[1]), pk2(a[2], a[3]), pk2(b[0], b[1]), pk2(b[2], b[3]) };
      *(v4u*)d = o;
    }
  }
}

#define LDX_S 136   // 128 + 8 pad shorts
#define LDH_S 264   // 256 + 8 pad shorts
#define LDP_S 40    // 32 slots + 8 pad floats
#define XBUF (64 * LDX_S)   // 8704 shorts / buffer
#define HBUF (64 * LDH_S)   // 16896 shorts / buffer
#define PBUF (64 * LDP_S)   // 2560 floats / buffer
#define SMEM_BYTES (2*XBUF*2 + 2*HBUF*2 + 2*PBUF*4)   // 122880

// v16 = v12's proven structure at 3 WAVES/SIMD. Diagnosis chain (v12-v15):
// latency-bound, both pipes ~50%, and the 2-wave/SIMD ceiling came only from
// B-waves holding 64 W2 rows (128 VGPR). v16 splits W2 across EIGHT B-waves
// (32 rows = 64 VGPR each): block = 768 thr = 12 waves (4 A + 8 B), 1 blk/CU,
// 3 waves/SIMD (VGPR cap 170; A~105, B~110 demand -- far from spill cliff).
// Role map w%3==0 -> A gives 1A+2B per SIMD under both contiguous and
// round-robin wave->SIMD conventions. Per-SIMD MFMA work unchanged (192);
// H-fragment reads now 8-way duplicated -> LDS ~3050 cyc/phase, still under
// MFMA's 3725 -> critical pipe unchanged, 3rd wave hides the latency.
// Pipeline, inner loops, pack layout, gather: v12 verbatim.
__global__ __launch_bounds__(768, 3) void mlp_v16(
    const short* __restrict__ xub, const short* __restrict__ xmb,
    const void* __restrict__ eidx,
    const short* __restrict__ pW1, const short* __restrict__ pW2,
    const float* __restrict__ b1, const float* __restrict__ b2,
    const float* __restrict__ W3, const float* __restrict__ b3,
    float* __restrict__ out, int E)
{
  extern __shared__ __align__(16) char smem[];
  short* ldsX = (short*)smem;                       // [2][XBUF]
  short* ldsH = (short*)(smem + 2 * XBUF * 2);      // [2][HBUF]
  float* ldsP = (float*)(smem + 2 * XBUF * 2 + 2 * HBUF * 2); // [2][PBUF]

  const int t    = threadIdx.x;
  const int w    = t >> 6;        // 0..11
  const int lane = t & 63;
  const int quad = lane >> 4;
  const int lp   = lane & 15;
  const bool isA = ((w % 3) == 0);     // waves 0,3,6,9 -> 1 A per SIMD either mapping

  const unsigned* ew = (const unsigned*)eidx;
  unsigned oddw = (lane < 32) ? ew[2 * lane + 1] : 0u;
  const bool i64 = (__ballot(oddw != 0u) == 0ull);

  const int ntiles = (E + 63) >> 6;
  const int S   = (int)gridDim.x;
  const int bid = (int)blockIdx.x;
  const int Tb  = (ntiles - bid + S - 1) / S;
  const float bias3 = b3[0];

  if (isA) {
    // ===== producer: gather (bf16) + layer 1 (+ store on wg==0) =====
    const int wg = w / 3;               // 0..3
    const v8s* w1v = (const v8s*)pW1;
    v8s rW1[4][4];                      // 64 VGPR
#pragma unroll
    for (int mi = 0; mi < 4; ++mi)
#pragma unroll
      for (int kt = 0; kt < 4; ++kt)
        rW1[mi][kt] = w1v[(((wg * 4 + mi) * 4) + kt) * 64 + lane];
    v4f rb1[4];
#pragma unroll
    for (int mi = 0; mi < 4; ++mi)
      rb1[mi] = *(const v4f*)(b1 + wg * 64 + mi * 16 + quad * 4);

    const int ra = wg * 64 + lane;      // 4 threads/edge
    const int gi = ra >> 2, gq = ra & 3;

    auto loadIdx = [&](int tl, int& row, int& col) {
      int gE = tl * 64 + gi;
      if (gE >= E || gE < 0) gE = 0;
      if (i64) {
        const long long* p = (const long long*)eidx;
        row = (int)p[gE]; col = (int)p[(long long)E + gE];
      } else {
        const int* p = (const int*)eidx;
        row = p[gE]; col = p[E + gE];
      }
    };

    v4u u0, u1, m0, m1;
    auto issueUM = [&](int row, int col) {
      const v4u* pu = (const v4u*)(xub + (size_t)row * 64 + gq * 16);
      const v4u* pm = (const v4u*)(xmb + (size_t)col * 64 + gq * 16);
      u0 = pu[0]; u1 = pu[1]; m0 = pm[0]; m1 = pm[1];
    };

    int rowN, colN;
    loadIdx(bid, rowN, colN);
    issueUM(rowN, colN);
    loadIdx(bid + S, rowN, colN);

    for (int k = 0; k <= Tb + 2; ++k) {
      __syncthreads();
      const int pb = k & 1;
      const int tg = bid + k * S;

      // ---- commit prefetched bf16 features -> ldsX[pb]
      if (k < Tb) {
        short* px = &ldsX[pb * XBUF + gi * LDX_S + gq * 16];
        *(v4u*)(px)      = u0;  *(v4u*)(px + 8)  = u1;   // user  -> k 0..63
        *(v4u*)(px + 64) = m0;  *(v4u*)(px + 72) = m1;   // movie -> k 64..127
      }
      // ---- prefetch features(t_{k+1}), indices(t_{k+2})
      if (k + 1 < Tb) {
        issueUM(rowN, colN);
        loadIdx(tg + 2 * S, rowN, colN);
      }

      // ---- reduce + store tile t3 from ldsP[pb^1] (wave wg==0, lane = edge)
      const int t3 = tg - 3 * S;
      if (t3 >= 0 && wg == 0) {
        const v4f* pp = (const v4f*)&ldsP[(pb ^ 1) * PBUF + lane * LDP_S];
        float r = bias3;
#pragma unroll
        for (int c = 0; c < 8; ++c) {
          v4f p = pp[c];
          r += (p[0] + p[1]) + (p[2] + p[3]);
        }
        int o = t3 * 64 + lane;
        if (o < E) out[o] = r;
      }

      // ---- layer 1 of t1 : ldsX[pb^1] -> ldsH[pb^1]
      const int t1 = tg - S;
      if (t1 >= 0 && t1 < ntiles) {
        const short* xb = &ldsX[(pb ^ 1) * XBUF];
#pragma unroll 1
        for (int nh = 0; nh < 2; ++nh) {       // ni halves: acc live = 32 VGPR
          v4f acc[4][2];
#pragma unroll
          for (int mi = 0; mi < 4; ++mi) { acc[mi][0] = rb1[mi]; acc[mi][1] = rb1[mi]; }
          __builtin_amdgcn_s_setprio(1);
#pragma unroll
          for (int kt = 0; kt < 4; ++kt) {
            v8s bf0 = *(const v8s*)&xb[((nh * 2 + 0) * 16 + lp) * LDX_S + kt * 32 + quad * 8];
            v8s bf1 = *(const v8s*)&xb[((nh * 2 + 1) * 16 + lp) * LDX_S + kt * 32 + quad * 8];
#pragma unroll
            for (int mi = 0; mi < 4; ++mi) {
              acc[mi][0] = __builtin_amdgcn_mfma_f32_16x16x32_bf16(rW1[mi][kt], bf0, acc[mi][0], 0, 0, 0);
              acc[mi][1] = __builtin_amdgcn_mfma_f32_16x16x32_bf16(rW1[mi][kt], bf1, acc[mi][1], 0, 0, 0);
            }
          }
          __builtin_amdgcn_s_setprio(0);
#pragma unroll
          for (int mi = 0; mi < 4; ++mi) {
            int nh0 = wg * 64 + mi * 16 + quad * 4;
#pragma unroll
            for (int nj = 0; nj < 2; ++nj) {
              int e = (nh * 2 + nj) * 16 + lp;
              v4f v = acc[mi][nj];
              v2u pw; pw.x = pk2(fmaxf(v[0], 0.f), fmaxf(v[1], 0.f));
              pw.y = pk2(fmaxf(v[2], 0.f), fmaxf(v[3], 0.f));
              *(v2u*)&ldsH[(pb ^ 1) * HBUF + e * LDH_S + nh0] = pw;
            }
          }
        }
      }
    }
  } else {
    // ===== consumer: layer 2 (32-row slice) + bias/ReLU + W3 fold =====
    const int bi = (w / 3) * 2 + (w % 3) - 1;   // 0..7 : rows bi*32..bi*32+31
    const v8s* w2v = (const v8s*)pW2;
    v8s rW2[2][8];                      // 64 VGPR
#pragma unroll
    for (int mi = 0; mi < 2; ++mi)
#pragma unroll
      for (int kt = 0; kt < 8; ++kt)
        rW2[mi][kt] = w2v[(((bi * 2 + mi) * 8) + kt) * 64 + lane];
    v4f rb2[2], rw3[2];
#pragma unroll
    for (int mi = 0; mi < 2; ++mi) {
      int nh0 = bi * 32 + mi * 16 + quad * 4;
      rb2[mi] = *(const v4f*)(b2 + nh0);
      rw3[mi] = *(const v4f*)(W3 + nh0);
    }

    for (int k = 0; k <= Tb + 2; ++k) {
      __syncthreads();
      const int pb = k & 1;
      const int tg = bid + k * S;
      const int t2 = tg - 2 * S;
      if (t2 >= 0 && t2 < ntiles) {
        const short* hbr = &ldsH[pb * HBUF];
        float* pPw = &ldsP[pb * PBUF];
#pragma unroll 1
        for (int nh = 0; nh < 2; ++nh) {       // ni halves: acc live = 16 VGPR
          v4f acc2[2][2];
#pragma unroll
          for (int mi = 0; mi < 2; ++mi) { acc2[mi][0] = rb2[mi]; acc2[mi][1] = rb2[mi]; }
          __builtin_amdgcn_s_setprio(1);
#pragma unroll
          for (int kt = 0; kt < 8; ++kt) {
            v8s bf0 = *(const v8s*)&hbr[((nh * 2 + 0) * 16 + lp) * LDH_S + kt * 32 + quad * 8];
            v8s bf1 = *(const v8s*)&hbr[((nh * 2 + 1) * 16 + lp) * LDH_S + kt * 32 + quad * 8];
#pragma unroll
            for (int mi = 0; mi < 2; ++mi) {
              acc2[mi][0] = __builtin_amdgcn_mfma_f32_16x16x32_bf16(rW2[mi][kt], bf0, acc2[mi][0], 0, 0, 0);
              acc2[mi][1] = __builtin_amdgcn_mfma_f32_16x16x32_bf16(rW2[mi][kt], bf1, acc2[mi][1], 0, 0, 0);
            }
          }
          __builtin_amdgcn_s_setprio(0);
          float s0 = 0.f, s1 = 0.f;
#pragma unroll
          for (int mi = 0; mi < 2; ++mi) {
#pragma unroll
            for (int r = 0; r < 4; ++r) {
              s0 += fmaxf(acc2[mi][0][r], 0.f) * rw3[mi][r];
              s1 += fmaxf(acc2[mi][1][r], 0.f) * rw3[mi][r];
            }
          }
          int e0 = (nh * 2 + 0) * 16 + lp, e1 = (nh * 2 + 1) * 16 + lp;
          pPw[e0 * LDP_S + bi * 4 + quad] = s0;
          pPw[e1 * LDP_S + bi * 4 + quad] = s1;
        }
      }
    }
  }
}

extern "C" void kernel_launch(void* const* d_in, const int* in_sizes, int n_in,
                              void* d_out, int out_size, void* d_ws, size_t ws_size,
                              hipStream_t stream) {
  const float* xu  = (const float*)d_in[0];
  const float* xm  = (const float*)d_in[1];
  const void*  ei  = d_in[2];
  const float* W1  = (const float*)d_in[3];
  const float* b1  = (const float*)d_in[4];
  const float* W2  = (const float*)d_in[5];
  const float* b2  = (const float*)d_in[6];
  const float* W3  = (const float*)d_in[7];
  const float* b3  = (const float*)d_in[8];
  float* out = (float*)d_out;

  const int E  = in_sizes[2] / 2;
  const int Nu = in_sizes[0] / 64;
  const int Nm = in_sizes[1] / 64;

  short* pW1 = (short*)d_ws;          // 64 KB
  short* pW2 = pW1 + 32768;           // 128 KB
  short* xub = (short*)((char*)d_ws + 196608);
  short* xmb = xub + (size_t)Nu * 64;

  const int cvt_blocks = ((Nu + Nm) * 8 + 255) / 256;
  hipLaunchKernelGGL(prep, dim3(384 + cvt_blocks), dim3(256), 0, stream,
                     W1, W2, xu, xm, pW1, pW2, xub, xmb, Nu, Nm);

  hipFuncSetAttribute((const void*)mlp_v16,
                      hipFuncAttributeMaxDynamicSharedMemorySize, SMEM_BYTES);

  const int ntiles = (E + 63) / 64;
  const int nblk = ntiles < 256 ? ntiles : 256;
  hipLaunchKernelGGL(mlp_v16, dim3(nblk), dim3(768), SMEM_BYTES, stream,
                     xub, xmb, ei, pW1, pW2, b1, b2, W3, b3, out, E);
}